// Round 2
// baseline (356.928 us; speedup 1.0000x reference)
//
#include <hip/hip_runtime.h>
#include <stdint.h>

#define BS 4
#define NN 1024
#define GD 6
#define CIN 256
#define NH 8
#define DH 32
#define HID 16
#define MCS 64

#define PG_ELEMS (BS*NN*NN*GD)                 // 25165824
#define OUT_OFF  PG_ELEMS
#define MASK_OFF (PG_ELEMS + BS*NN*CIN)        // 26214400

typedef float vfloat4 __attribute__((ext_vector_type(4)));
typedef float vfloat2 __attribute__((ext_vector_type(2)));
typedef unsigned vuint4 __attribute__((ext_vector_type(4)));

#if __has_builtin(__builtin_amdgcn_rcpf)
__device__ __forceinline__ float fast_rcp(float x) { return __builtin_amdgcn_rcpf(x); }
#else
__device__ __forceinline__ float fast_rcp(float x) { return 1.0f / x; }
#endif
#if __has_builtin(__builtin_amdgcn_exp2f)
__device__ __forceinline__ float fast_exp2(float x) { return __builtin_amdgcn_exp2f(x); }
#else
__device__ __forceinline__ float fast_exp2(float x) { return exp2f(x); }
#endif
#define LOG2E 1.44269504088896340736f

// swish via v_exp_f32 + v_rcp_f32 (avoids IEEE divide sequence)
__device__ __forceinline__ float swishf(float x) {
    return x * fast_rcp(1.0f + fast_exp2(x * -LOG2E));
}

// Fused 4096x256 @ 256x256 + bias GEMM; blockIdx.y selects one of up to 3 (W,b,dst).
// RPB = rows per block (16 for the 3-way launch, 8 for the single launch -> 2 blocks/CU).
template<int RPB>
__global__ __launch_bounds__(256) void gemm3(const float* __restrict__ X,
    const float* __restrict__ W0, const float* __restrict__ B0, float* __restrict__ D0,
    const float* __restrict__ W1, const float* __restrict__ B1, float* __restrict__ D1,
    const float* __restrict__ W2, const float* __restrict__ B2, float* __restrict__ D2)
{
    const float* W; const float* Bv; float* D;
    if (blockIdx.y == 0)      { W = W0; Bv = B0; D = D0; }
    else if (blockIdx.y == 1) { W = W1; Bv = B1; D = D1; }
    else                      { W = W2; Bv = B2; D = D2; }
    const int tid = threadIdx.x;
    const int c4  = tid & 63;        // column quad: cols 4*c4 .. 4*c4+3
    const int rg  = tid >> 6;        // row group
    const int r0  = blockIdx.x * RPB;
    constexpr int RG = RPB / 4;      // rows per row-group (4 or 2)

    __shared__ float xsT[CIN][RPB + 4];   // [k][row], padded
    {
        float tmp[RPB];
        #pragma unroll
        for (int r = 0; r < RPB; ++r) tmp[r] = X[(size_t)(r0 + r)*CIN + tid];
        #pragma unroll
        for (int j = 0; j < RPB/4; ++j)
            *(vfloat4*)&xsT[tid][4*j] = (vfloat4){tmp[4*j+0], tmp[4*j+1], tmp[4*j+2], tmp[4*j+3]};
    }
    __syncthreads();

    vfloat4 acc[RG];
    #pragma unroll
    for (int r = 0; r < RG; ++r) acc[r] = (vfloat4){0.f,0.f,0.f,0.f};
    const vfloat4* W4 = (const vfloat4*)W;
    #pragma unroll 4
    for (int k = 0; k < CIN; ++k) {
        vfloat4 w = W4[(size_t)k*64 + c4];                  // coalesced 1 KB/wave
        if constexpr (RG == 4) {
            vfloat4 xr = *(const vfloat4*)&xsT[k][rg*4];    // wave-uniform broadcast b128
            acc[0] += xr.x * w;
            acc[1] += xr.y * w;
            acc[2] += xr.z * w;
            acc[3] += xr.w * w;
        } else {
            vfloat2 xr = *(const vfloat2*)&xsT[k][rg*2];    // wave-uniform broadcast b64
            acc[0] += xr.x * w;
            acc[1] += xr.y * w;
        }
    }
    vfloat4 bb = ((const vfloat4*)Bv)[c4];
    vfloat4* D4 = (vfloat4*)D;
    const size_t rbase = (size_t)(r0 + rg*RG);
    #pragma unroll
    for (int r = 0; r < RG; ++r) D4[(rbase + r)*64 + c4] = acc[r] + bb;
}

// One block per (query i, batch b).
__global__ __launch_bounds__(256, 8) void attn_topk(
    const float* __restrict__ pg, const int* __restrict__ mask,
    const float* __restrict__ lW1g, const float* __restrict__ lb1g,
    const float* __restrict__ lW2g, const float* __restrict__ lb2g,
    const float* __restrict__ lW3g, const float* __restrict__ lb3g,
    const float* __restrict__ Q, const float* __restrict__ Kc, const float* __restrict__ Vc,
    float* __restrict__ O, float* __restrict__ pg_out, float* __restrict__ mask_out)
{
    const int i = blockIdx.x, b = blockIdx.y, tid = threadIdx.x;
    const int lane = tid & 63;

    // union: select phase -> hist[256] u32 @0, eqlist[64] u32 @256 ; later -> sc[64][8] f32
    __shared__ __align__(16) unsigned selbuf[512];   // 2 KB
    __shared__ float sg[MCS*7];                      // compact nbhd_g, stride 7
    __shared__ int nj[MCS];                          // bit31 = invalid flag
    __shared__ __align__(16) unsigned joff[MCS];     // float4 row offsets into Q/K/V space
    __shared__ __align__(16) float scratch[1024];    // d2 accum early; output partials late (4 KB)
    __shared__ unsigned wsum[4];
    __shared__ unsigned sel_bin, sel_need, s_cnt, s_eqcnt;

    float (*sc)[NH]   = (float (*)[NH])selbuf;
    unsigned* hist    = selbuf;
    unsigned* eqlist  = selbuf + 256;

    const int* mrow = mask + b*NN;
    if (tid == 0) mask_out[b*NN + i] = mrow[i] ? 1.0f : 0.0f;

    // ---- single coalesced pg read; data held in regs for (a) dist^2, (b) late NT store ----
    const size_t rowoff = (size_t)(b*NN + i) * (NN*GD);
    const vfloat4* src4 = (const vfloat4*)(pg + rowoff);
    vfloat4* dst4 = (vfloat4*)(pg_out + rowoff);
    vfloat4 c0 = src4[tid      ], c1 = src4[tid +  256], c2 = src4[tid +  512],
            c3 = src4[tid + 768], c4 = src4[tid + 1024], c5 = src4[tid + 1280];
    vfloat4 q4 = ((const vfloat4*)Q)[(size_t)(b*NN + i)*64 + (tid & 63)];
    const int4 mv = ((const int4*)mrow)[tid];

    // zero the per-row dist^2 accumulator
    *(vfloat4*)&scratch[tid*4] = (vfloat4){0.f,0.f,0.f,0.f};
    __syncthreads();

    // ---- segmented squares: float4 #p covers elements 4p..4p+3 of the row-major [1024][6]
    //      grid; p%3==0 -> all 4 in row 2(p/3); p%3==1 -> 2+2 split; p%3==2 -> all 4 in row+1.
    const int tm3 = tid % 3;
    #define ACC_D2(v, t) do { \
        int p = tid + 256*(t); \
        int pm = tm3 + ((t) % 3); if (pm >= 3) pm -= 3; \
        int r0 = 2 * (int)(((unsigned)(p - pm)) * 0xAAAAAAABu); /* exact (p-pm)/3 */ \
        vfloat4 sq = (v)*(v); \
        float slo = sq.x + sq.y, shi = sq.z + sq.w; \
        bool split = (pm == 1); \
        int ra = r0 + ((pm == 2) ? 1 : 0); \
        atomicAdd(&scratch[ra], split ? slo : (slo + shi)); \
        if (split) atomicAdd(&scratch[r0 + 1], shi); \
    } while (0)
    ACC_D2(c0, 0); ACC_D2(c1, 1); ACC_D2(c2, 2);
    ACC_D2(c3, 3); ACC_D2(c4, 4); ACC_D2(c5, 5);
    #undef ACC_D2
    __syncthreads();

    // keys for rows 4*tid..4*tid+3
    const int vb[4] = { mv.x, mv.y, mv.z, mv.w };
    unsigned key[4];
    {
        vfloat4 dd = *(const vfloat4*)&scratch[tid*4];
        float dv[4] = { dd.x, dd.y, dd.z, dd.w };
        #pragma unroll
        for (int r = 0; r < 4; ++r)
            key[r] = __float_as_uint(vb[r] ? dv[r] : 1e30f);
    }

    // ---- 4-level radix select: find exact 64-smallest threshold ----
    unsigned prefix = 0;
    int need = MCS;
    for (int level = 0; level < 4; ++level) {
        const int shift = 24 - 8*level;
        hist[tid] = 0;
        __syncthreads();
        if (level == 0) {
            #pragma unroll
            for (int r = 0; r < 4; ++r) {
                unsigned d = key[r] >> 24;
                unsigned long long todo = __ballot(true);
                while (todo) {
                    int leader = (int)(__ffsll((unsigned long long)todo) - 1);
                    unsigned dl = __shfl(d, leader);
                    unsigned long long match = __ballot(d == dl);
                    if (lane == leader) atomicAdd(&hist[dl], (unsigned)__popcll(match));
                    todo &= ~match;
                }
            }
        } else {
            const unsigned pmask = 0xFFFFFFFFu << (shift + 8);
            #pragma unroll
            for (int r = 0; r < 4; ++r)
                if ((key[r] & pmask) == prefix)
                    atomicAdd(&hist[(key[r] >> shift) & 0xFFu], 1u);
        }
        __syncthreads();
        unsigned own = hist[tid];
        unsigned v = own;
        #pragma unroll
        for (int off = 1; off < 64; off <<= 1) {
            unsigned nv = __shfl_up(v, off);
            if (lane >= off) v += nv;
        }
        if (lane == 63) wsum[tid >> 6] = v;
        __syncthreads();
        unsigned basec = 0;
        for (int w = 0; w < (tid >> 6); ++w) basec += wsum[w];
        unsigned incl = v + basec;
        unsigned excl = incl - own;
        if (excl < (unsigned)need && (unsigned)need <= incl) {
            sel_bin = (unsigned)tid;
            sel_need = (unsigned)need - excl;
        }
        __syncthreads();
        prefix |= (sel_bin << shift);
        need = (int)sel_need;
    }
    const unsigned T = prefix;
    const int needT = need;

    if (tid == 0) { s_cnt = 0; s_eqcnt = 0; }
    __syncthreads();
    // ---- compaction: indices only (g-values gathered afterwards from L2-warm pg) ----
    #pragma unroll
    for (int r = 0; r < 4; ++r) {
        unsigned kk = key[r];
        int j = tid*4 + r;
        if (kk < T) {
            unsigned p = atomicAdd(&s_cnt, 1u);
            nj[p] = j | (vb[r] ? 0 : (int)0x80000000);
        } else if (kk == T) {
            unsigned e = atomicAdd(&s_eqcnt, 1u);
            if (e < 64) eqlist[e] = (unsigned)j;
        }
    }
    __syncthreads();
    const int cbase = (int)s_cnt;
    if (tid == 0) {
        int ec = (int)s_eqcnt; if (ec > 64) ec = 64;
        for (int s2 = 0; s2 < needT; ++s2) {
            int bi = -1, bj = 0x7FFFFFFF;
            for (int e = 0; e < ec; ++e) {
                int jj = (int)eqlist[e];
                if (jj < bj) { bj = jj; bi = e; }
            }
            if (bi >= 0) {
                eqlist[bi] = 0x7FFFFFFFu;
                nj[cbase + s2] = bj | (mrow[bj] ? 0 : (int)0x80000000);
            }
        }
    }
    __syncthreads();
    // ---- gather g-values of the 64 selected rows (L2/L3-warm; 24 B each) + row offsets ----
    if (tid < MCS) {
        int jm = nj[tid] & 0x7FFFFFFF;
        joff[tid] = ((unsigned)(b*NN + jm)) << 6;
        const float* gp = pg + rowoff + (size_t)jm * 6;     // 8B-aligned
        vfloat2 g01 = *(const vfloat2*)gp;
        vfloat2 g23 = *(const vfloat2*)(gp + 2);
        vfloat2 g45 = *(const vfloat2*)(gp + 4);
        float* sgp = sg + tid*7;
        sgp[0] = g01.x; sgp[1] = g01.y; sgp[2] = g23.x;
        sgp[3] = g23.y; sgp[4] = g45.x; sgp[5] = g45.y;
    }
    __syncthreads();   // nj+sg+joff ready; selbuf now reusable as sc[][]

    // ---- passthrough NT store, deferred: the MLP below hides the vmcnt drain at the
    //      next barrier instead of the radix barriers stalling on 96 KB of writes ----
    __builtin_nontemporal_store(c0, &dst4[tid      ]);
    __builtin_nontemporal_store(c1, &dst4[tid +  256]);
    __builtin_nontemporal_store(c2, &dst4[tid +  512]);
    __builtin_nontemporal_store(c3, &dst4[tid +  768]);
    __builtin_nontemporal_store(c4, &dst4[tid + 1024]);
    __builtin_nontemporal_store(c5, &dst4[tid + 1280]);

    __builtin_amdgcn_s_setprio(1);
    // ---- location-kernel MLP: wave-uniform head -> scalar (s_load) weights ----
    #pragma unroll
    for (int pass = 0; pass < 2; ++pass) {
        const int h = __builtin_amdgcn_readfirstlane((tid >> 6) + pass*4);   // 0..7
        const int m = lane;
        const float* W1h = lW1g + h*(GD*HID);
        const float* B1h = lb1g + h*HID;
        const float* W2h = lW2g + h*(HID*HID);
        const float* B2h = lb2g + h*HID;
        const float* W3h = lW3g + h*HID;
        float gv[GD];
        #pragma unroll
        for (int g = 0; g < GD; ++g) gv[g] = sg[m*7 + g];
        float h1[HID];
        #pragma unroll
        for (int kk = 0; kk < HID; ++kk) {
            float a = B1h[kk];
            #pragma unroll
            for (int g = 0; g < GD; ++g) a += gv[g] * W1h[g*HID + kk];
            h1[kk] = swishf(a);
        }
        float h2[HID];
        #pragma unroll
        for (int l = 0; l < HID; ++l) {
            float a = B2h[l];
            #pragma unroll
            for (int kk = 0; kk < HID; ++kk) a += h1[kk] * W2h[kk*HID + l];
            h2[l] = swishf(a);
        }
        float a3 = lb3g[h];
        #pragma unroll
        for (int kk = 0; kk < HID; ++kk) a3 += h2[kk] * W3h[kk];
        sc[m][h] = (nj[m] < 0) ? -1e38f : swishf(a3);
    }
    __syncthreads();

    // ---- feat: wave p owns m = 16p..16p+15; lane q owns channel quad 4q..4q+3. ----
    const int q = tid & 63;
    const int p = tid >> 6;
    const int hh = q >> 3;                 // head of this channel quad
    q4 *= 0.17677669529663688f;            // fold 1/sqrt(32) into q
    const vfloat4* Kc4 = (const vfloat4*)Kc;
    const vuint4* jo4 = (const vuint4*)(joff + (p << 4));
    #pragma unroll
    for (int mg = 0; mg < 4; ++mg) {
        vuint4 o4 = jo4[mg];
        #pragma unroll
        for (int r = 0; r < 4; ++r) {
            const int mm = (p << 4) + (mg << 2) + r;
            vfloat4 kv = Kc4[o4[r] + (unsigned)q];
            float d = q4.x * kv.x;
            d = fmaf(q4.y, kv.y, d);
            d = fmaf(q4.z, kv.z, d);
            d = fmaf(q4.w, kv.w, d);
            d += __shfl_xor(d, 1);
            d += __shfl_xor(d, 2);
            d += __shfl_xor(d, 4);
            if ((q & 7) == 0) sc[mm][hh] += d;   // one lane per (m,h); -1e38 stays -1e38
        }
    }
    __syncthreads();

    // ---- softmax over m, wave-parallel: lane = m, wave (x2 passes) = head ----
    #pragma unroll
    for (int pass = 0; pass < 2; ++pass) {
        int h = (tid >> 6) + pass*4;
        float s = sc[lane][h];
        float mx = s;
        #pragma unroll
        for (int off = 32; off; off >>= 1) mx = fmaxf(mx, __shfl_xor(mx, off));
        float e = fast_exp2((s - mx) * LOG2E);
        float sum = e;
        #pragma unroll
        for (int off = 32; off; off >>= 1) sum += __shfl_xor(sum, off);
        sc[lane][h] = e * fast_rcp(sum);
    }
    __syncthreads();

    // ---- out: same partition; coalesced float4 V loads; 4 wave-partials reduced in LDS ----
    {
        const vfloat4* Vc4 = (const vfloat4*)Vc;
        vfloat4 acc = (vfloat4){0.f,0.f,0.f,0.f};
        #pragma unroll
        for (int mg = 0; mg < 4; ++mg) {
            vuint4 o4 = jo4[mg];
            #pragma unroll
            for (int r = 0; r < 4; ++r) {
                const int mm = (p << 4) + (mg << 2) + r;
                float a = sc[mm][hh];
                vfloat4 v4 = Vc4[o4[r] + (unsigned)q];
                acc += a * v4;
            }
        }
        __builtin_amdgcn_s_setprio(0);
        ((vfloat4*)scratch)[p*64 + q] = acc;    // scratch reused as output partials
    }
    __syncthreads();
    {
        const float* ob = scratch;
        float s = ob[tid] + ob[256 + tid] + ob[512 + tid] + ob[768 + tid];
        O[(size_t)(b*NN + i)*CIN + tid] = s;
    }
}

extern "C" void kernel_launch(void* const* d_in, const int* in_sizes, int n_in,
                              void* d_out, int out_size, void* d_ws, size_t ws_size,
                              hipStream_t stream) {
    const float* pg   = (const float*)d_in[0];
    const float* x    = (const float*)d_in[1];
    const int*   mask = (const int*)d_in[2];
    const float* lW1  = (const float*)d_in[3];
    const float* lb1  = (const float*)d_in[4];
    const float* lW2  = (const float*)d_in[5];
    const float* lb2  = (const float*)d_in[6];
    const float* lW3  = (const float*)d_in[7];
    const float* lb3  = (const float*)d_in[8];
    const float* Wq   = (const float*)d_in[9];
    const float* bq   = (const float*)d_in[10];
    const float* Wk   = (const float*)d_in[11];
    const float* bk   = (const float*)d_in[12];
    const float* Wv   = (const float*)d_in[13];
    const float* bv   = (const float*)d_in[14];
    const float* Wo   = (const float*)d_in[15];
    const float* bo   = (const float*)d_in[16];

    float* out = (float*)d_out;
    float* Q  = (float*)d_ws;
    float* Kc = Q  + (size_t)BS*NN*CIN;
    float* Vc = Kc + (size_t)BS*NN*CIN;
    float* O  = Vc + (size_t)BS*NN*CIN;

    // QKV projections (z = 0,1,2)
    gemm3<16><<<dim3(BS*NN/16, 3), 256, 0, stream>>>(x, Wq, bq, Q, Wk, bk, Kc, Wv, bv, Vc);
    // top-k + attention (also performs the pairwise_g passthrough copy + mask write)
    attn_topk<<<dim3(NN, BS), 256, 0, stream>>>(pg, mask, lW1, lb1, lW2, lb2, lW3, lb3,
                                                Q, Kc, Vc, O, out, out + MASK_OFF);
    // output projection: 8 rows/block -> 512 blocks -> 2 blocks/CU (was 1, latency-exposed)
    gemm3<8><<<dim3(BS*NN/8, 1), 256, 0, stream>>>(O, Wo, bo, out + OUT_OFF,
                                                   Wo, bo, out + OUT_OFF,
                                                   Wo, bo, out + OUT_OFF);
}